// Round 1
// 584.231 us; speedup vs baseline: 1.1839x; 1.1839x over previous
//
#include <hip/hip_runtime.h>

// FlowNet2 Resample2d (bilinear warp), B=8 C=32 H=512 W=512, float32.
//
// Round-2 layout change: LANE-CONSECUTIVE PIXELS. Previously thread t owned
// pixels 4t..4t+3 -> gather addresses strided 16B/lane -> each gather instr
// touched ~16-20 cache lines (address-throughput bound: VALUBusy 3.8%,
// hbm 26% of peak). Now each thread's 4 pixels are strided by BLOCK=256, so
// within a wave the 64 gather addresses are CONSECUTIVE pixels (4B/lane,
// ~5-6 lines/instr) -> ~3x fewer L1 line transactions.
//
// XCD swizzle: grid=2048 blocks, dispatch is round-robin over 8 XCDs.
// blk = (id%8)*256 + id/8 gives each XCD one contiguous 256-block chunk
// = exactly one batch image (256*1024 px = HW), so the +-dy halo rows of
// the gather are shared inside one XCD's L2 instead of re-fetched from HBM
// by up to 8 XCDs (FETCH_SIZE was 1.7x ideal).
//
// Nontemporal stores (output written once, 272MB) and flow loads (read once)
// keep streamed data from evicting reusable input1 lines in L2.

namespace {
constexpr int B = 8, C = 32, H = 512, W = 512;
constexpr int HW = H * W;                    // 262144 = 2^18
constexpr int NPIX = B * H * W;              // 2^21
constexpr int PPT = 4;                       // pixels per thread
constexpr int BLOCK = 256;
constexpr int PIX_PER_BLOCK = BLOCK * PPT;   // 1024 (2 rows)
constexpr int GRID = NPIX / PIX_PER_BLOCK;   // 2048 (exact, %8 == 0)
constexpr int NXCD = 8;
}

__global__ __launch_bounds__(BLOCK) void resample2d_kernel(
    const float* __restrict__ in1,   // [B,C,H,W]
    const float* __restrict__ flow,  // [B,2,H,W] ch0=dx ch1=dy
    float* __restrict__ out)         // [B,C,H,W]
{
    // Bijective XCD-contiguous remap (2048 % 8 == 0).
    const int blk = (int)((blockIdx.x % NXCD) * (GRID / NXCD) + blockIdx.x / NXCD);
    const int tid = (int)threadIdx.x;

    const int b     = blk >> 8;                      // 256 blocks per image
    const int lbase = (blk & 255) * PIX_PER_BLOCK;   // within-plane pixel base

    const float* __restrict__ flowp = flow + (size_t)(b * 2) * HW;

    float wt[PPT][4];
    int   of[PPT][4];
    int   op[PPT];

#pragma unroll
    for (int j = 0; j < PPT; ++j) {
        const int p = lbase + j * BLOCK + tid;   // within-plane pixel index
        op[j] = p;
        const int w = p & (W - 1);
        const int h = p >> 9;
        const float dx = __builtin_nontemporal_load(flowp + p);
        const float dy = __builtin_nontemporal_load(flowp + p + HW);
        const float xf = (float)w + dx;
        const float yf = (float)h + dy;
        const float x0 = floorf(xf);
        const float y0 = floorf(yf);
        // Weights from UNCLAMPED fractional coords (matches reference).
        const float alpha = xf - x0;
        const float beta  = yf - y0;
        const int x0i = (int)x0;
        const int y0i = (int)y0;
        const int xL = min(max(x0i,     0), W - 1);
        const int xR = min(max(x0i + 1, 0), W - 1);
        const int yT = min(max(y0i,     0), H - 1);
        const int yB = min(max(y0i + 1, 0), H - 1);
        wt[j][0] = (1.0f - alpha) * (1.0f - beta);
        wt[j][1] = alpha * (1.0f - beta);
        wt[j][2] = (1.0f - alpha) * beta;
        wt[j][3] = alpha * beta;
        of[j][0] = yT * W + xL;
        of[j][1] = yT * W + xR;
        of[j][2] = yB * W + xL;
        of[j][3] = yB * W + xR;
    }

    const float* __restrict__ inb  = in1 + (size_t)b * C * HW;
    float* __restrict__       outb = out + (size_t)b * C * HW;

#pragma unroll 2
    for (int c = 0; c < C; ++c) {
        const float* __restrict__ p = inb  + (size_t)c * HW;
        float* __restrict__       q = outb + (size_t)c * HW;
#pragma unroll
        for (int j = 0; j < PPT; ++j) {
            const float r = wt[j][0] * p[of[j][0]] + wt[j][1] * p[of[j][1]]
                          + wt[j][2] * p[of[j][2]] + wt[j][3] * p[of[j][3]];
            __builtin_nontemporal_store(r, q + op[j]);
        }
    }
}

extern "C" void kernel_launch(void* const* d_in, const int* in_sizes, int n_in,
                              void* d_out, int out_size, void* d_ws, size_t ws_size,
                              hipStream_t stream) {
    const float* in1  = (const float*)d_in[0];
    const float* flow = (const float*)d_in[1];
    float* out = (float*)d_out;
    resample2d_kernel<<<GRID, BLOCK, 0, stream>>>(in1, flow, out);
}

// Round 2
// 577.025 us; speedup vs baseline: 1.1987x; 1.0125x over previous
//
#include <hip/hip_runtime.h>

// FlowNet2 Resample2d (bilinear warp), B=8 C=32 H=512 W=512, float32.
//
// Round-3: PAIRED-TAP GATHERS. Counter evidence (r1): hbm 18% of peak,
// VALU 7%, MFMA 0, yet 283us/dispatch -> bound by L1 miss/transaction
// throughput (~6.5 cyc per missing line per CU), not bytes. The L and R
// taps of each pixel are adjacent floats; issuing them as two scalar
// loads doubles the L1 lookups for the same line(s). Merge each row's
// tap pair into ONE global_load_dwordx2 at base xb = clamp(x0i, 0, W-2):
//   x0i < 0    -> both taps clamp to col 0   -> (fa,fb) = (1, 0)
//   x0i >= W-1 -> both taps clamp to col W-1 -> (fa,fb) = (0, 1)   [v1 = p[W-1]]
//   else       -> (fa,fb) = (1-alpha, alpha)
// ((1-a)+a = 1 makes the clamped cases exact.) Gather instrs/wave: 512->256.
//
// Kept from r2 (each independently supported by counters):
//  - lane-consecutive pixels (thread's 4 pixels strided by BLOCK): gather
//    span 256B/instr instead of 1KB.
//  - XCD-contiguous block swizzle (one batch image per XCD): FETCH_SIZE
//    dropped 481MB -> 144MB.
//  - nontemporal flow loads + output stores (streamed once; input1 is
//    exactly 256MiB and lives in Infinity Cache between dispatches).

namespace {
constexpr int B = 8, C = 32, H = 512, W = 512;
constexpr int HW = H * W;                    // 262144 = 2^18
constexpr int NPIX = B * H * W;              // 2^21
constexpr int PPT = 4;                       // pixels per thread
constexpr int BLOCK = 256;
constexpr int PIX_PER_BLOCK = BLOCK * PPT;   // 1024 (2 rows)
constexpr int GRID = NPIX / PIX_PER_BLOCK;   // 2048 (exact, %8 == 0)
constexpr int NXCD = 8;
}

__global__ __launch_bounds__(BLOCK) void resample2d_kernel(
    const float* __restrict__ in1,   // [B,C,H,W]
    const float* __restrict__ flow,  // [B,2,H,W] ch0=dx ch1=dy
    float* __restrict__ out)         // [B,C,H,W]
{
    // Bijective XCD-contiguous remap (2048 % 8 == 0).
    const int blk = (int)((blockIdx.x % NXCD) * (GRID / NXCD) + blockIdx.x / NXCD);
    const int tid = (int)threadIdx.x;

    const int b     = blk >> 8;                      // 256 blocks per image
    const int lbase = (blk & 255) * PIX_PER_BLOCK;   // within-plane pixel base

    const float* __restrict__ flowp = flow + (size_t)(b * 2) * HW;

    float wt[PPT][4];   // fused x-pair * y weights: {fa*(1-b), fb*(1-b), fa*b, fb*b}
    int   of[PPT][2];   // dwordx2 base offsets: {top row, bottom row}
    int   op[PPT];

#pragma unroll
    for (int j = 0; j < PPT; ++j) {
        const int p = lbase + j * BLOCK + tid;   // within-plane pixel index
        op[j] = p;
        const int w = p & (W - 1);
        const int h = p >> 9;
        const float dx = __builtin_nontemporal_load(flowp + p);
        const float dy = __builtin_nontemporal_load(flowp + p + HW);
        const float xf = (float)w + dx;
        const float yf = (float)h + dy;
        const float x0 = floorf(xf);
        const float y0 = floorf(yf);
        // Weights from UNCLAMPED fractional coords (matches reference).
        const float alpha = xf - x0;
        const float beta  = yf - y0;
        const int x0i = (int)x0;
        const int y0i = (int)y0;
        const int yT = min(max(y0i,     0), H - 1);
        const int yB = min(max(y0i + 1, 0), H - 1);
        const int xb = min(max(x0i, 0), W - 2);      // pair base column
        // x-direction pair factors (exact for border-clamped taps).
        const float fa = (x0i < 0) ? 1.0f : ((x0i >= W - 1) ? 0.0f : 1.0f - alpha);
        const float fb = (x0i < 0) ? 0.0f : ((x0i >= W - 1) ? 1.0f : alpha);
        const float bT = 1.0f - beta;
        wt[j][0] = fa * bT;
        wt[j][1] = fb * bT;
        wt[j][2] = fa * beta;
        wt[j][3] = fb * beta;
        of[j][0] = yT * W + xb;
        of[j][1] = yB * W + xb;
    }

    const float* __restrict__ inb  = in1 + (size_t)b * C * HW;
    float* __restrict__       outb = out + (size_t)b * C * HW;

#pragma unroll 2
    for (int c = 0; c < C; ++c) {
        const float* __restrict__ p = inb  + (size_t)c * HW;
        float* __restrict__       q = outb + (size_t)c * HW;
#pragma unroll
        for (int j = 0; j < PPT; ++j) {
            const float2 vT = *reinterpret_cast<const float2*>(p + of[j][0]);
            const float2 vB = *reinterpret_cast<const float2*>(p + of[j][1]);
            const float r = wt[j][0] * vT.x + wt[j][1] * vT.y
                          + wt[j][2] * vB.x + wt[j][3] * vB.y;
            __builtin_nontemporal_store(r, q + op[j]);
        }
    }
}

extern "C" void kernel_launch(void* const* d_in, const int* in_sizes, int n_in,
                              void* d_out, int out_size, void* d_ws, size_t ws_size,
                              hipStream_t stream) {
    const float* in1  = (const float*)d_in[0];
    const float* flow = (const float*)d_in[1];
    float* out = (float*)d_out;
    resample2d_kernel<<<GRID, BLOCK, 0, stream>>>(in1, flow, out);
}